// Round 20
// baseline (254.049 us; speedup 1.0000x reference)
//
#include <hip/hip_runtime.h>
#include <math.h>

#define VEC   300
#define HID   256
#define ATT   500
#define NB    64
#define NS    128
#define G3    768     // 3*HID
#define GIC   1536    // both directions packed
#define H2    512     // 2*HID
#define KP    320     // K padded for MFMA (10 x 32)

typedef _Float16 half1;
typedef _Float16 h2_t  __attribute__((ext_vector_type(2)));
typedef _Float16 f16x8 __attribute__((ext_vector_type(8)));
typedef float    f32x4 __attribute__((ext_vector_type(4)));

struct __align__(16) H8 { h2_t a, b, c, d; };

#if __has_builtin(__builtin_amdgcn_exp2f)
#define EXP2F(x) __builtin_amdgcn_exp2f(x)
#else
#define EXP2F(x) exp2f(x)
#endif
#if __has_builtin(__builtin_amdgcn_rcpf)
#define RCPF(x) __builtin_amdgcn_rcpf(x)
#else
#define RCPF(x) (1.0f/(x))
#endif

__device__ __forceinline__ float sigm(float x){ return RCPF(1.f + EXP2F(-1.44269504f*x)); }
__device__ __forceinline__ float tanh_fast(float x){ return 1.f - 2.f*RCPF(1.f + EXP2F(2.88539008f*x)); }

#if __has_builtin(__builtin_amdgcn_fdot2)
#define FDOT(w,h,acc) __builtin_amdgcn_fdot2((w),(h),(acc),false)
#else
#define FDOT(w,h,acc) ((acc) + (float)(w).x*(float)(h).x + (float)(w).y*(float)(h).y)
#endif

// ---- merged prep: [0] Whh pack (u-pair/4-way-k layout), [1] afW16, [2] xe16, [3] W16.
// Scan thread t (0..511): w=t>>6, lane=t&63, ul=lane&15, ks=(lane>>4)&3,
// u0=w*32+ul*2, uu in {0,1}; slot (dir*192 + p*6 + uu*3 + j)*512 + t holds
// rows k0=ks*64+2p,+1 of gate j, column u0+uu.
#define N_WPK 196608
#define N_AFW 262144
#define N_XE  1310720
#define N_W16 245760
__global__ __launch_bounds__(256) void k_prep_all(const int* __restrict__ x,
      const float* __restrict__ emb,
      const float* __restrict__ Wih_f, const float* __restrict__ Wih_b,
      const float* __restrict__ Whh_f, const float* __restrict__ Whh_b,
      const float* __restrict__ afW,
      h2_t* __restrict__ Wpk, half1* __restrict__ afW16,
      h2_t* __restrict__ xe16, h2_t* __restrict__ W16){
  int o = blockIdx.x*256 + threadIdx.x;
  if (o < N_WPK) {
    int t = o & 511;
    int rest = o >> 9;                   // dir*192 + p*6 + uu*3 + j
    int dir = rest / 192;
    int r2  = rest - dir*192;
    int p   = r2 / 6;
    int r3  = r2 - p*6;
    int uu  = r3 / 3;
    int j   = r3 - uu*3;
    int ul = t & 15, ks = (t >> 4) & 3, w = t >> 6;
    int u = w*32 + ul*2 + uu;
    const float* W = dir ? Whh_b : Whh_f;
    int k0 = ks*64 + 2*p;
    h2_t wv;
    wv.x = (half1)W[(j*HID+u)*HID + k0];
    wv.y = (half1)W[(j*HID+u)*HID + k0 + 1];
    Wpk[o] = wv;
    return;
  }
  o -= N_WPK;
  if (o < N_AFW) {
    int n = o >> 9, k = o & 511;
    afW16[o] = (half1)((n < ATT) ? afW[n*H2 + k] : 0.f);
    return;
  }
  o -= N_AFW;
  if (o < N_XE) {
    int i = o / 160, kp = o - 160*(o/160);
    int k0 = kp*2;
    int s = i >> 6, b = i & 63;
    h2_t v; v.x = (half1)0.f; v.y = (half1)0.f;
    if (k0 < VEC) {
      const float* e = &emb[(long)x[b*NS + s]*VEC];
      v.x = (half1)e[k0];
      v.y = (half1)((k0+1 < VEC) ? e[k0+1] : 0.f);
    }
    xe16[(long)i*160 + kp] = v;
    return;
  }
  o -= N_XE;
  if (o < N_W16) {
    int g = o / 160, kp = o - 160*(o/160);
    int k0 = kp*2;
    h2_t v; v.x = (half1)0.f; v.y = (half1)0.f;
    if (k0 < VEC) {
      const float* wr = (g < G3) ? &Wih_f[(long)g*VEC] : &Wih_b[(long)(g-G3)*VEC];
      v.x = (half1)wr[k0];
      v.y = (half1)((k0+1 < VEC) ? wr[k0+1] : 0.f);
    }
    W16[(long)g*160 + kp] = v;
  }
}

// ---- input projection: MFMA GEMM, fragments direct from global (L2-resident).
__global__ __launch_bounds__(256)
__attribute__((amdgpu_waves_per_eu(4, 4)))
void k_gi16f(const half1* __restrict__ xe16, const half1* __restrict__ W16,
      const float* __restrict__ bf, const float* __restrict__ bb,
      float* __restrict__ gi){
  const int t = threadIdx.x;
  const int row0 = blockIdx.x * 128;
  const int col0 = blockIdx.y * 128;
  const int lane = t & 63, wid = t >> 6;
  const int wr = wid >> 1, wc = wid & 1;
  const int l15 = lane & 15, lk = lane >> 4;

  f32x4 acc[4][4];
#pragma unroll
  for (int i = 0; i < 4; ++i)
#pragma unroll
    for (int j = 0; j < 4; ++j) acc[i][j] = (f32x4){0.f,0.f,0.f,0.f};

#pragma unroll 1
  for (int ks = 0; ks < 10; ++ks) {
    f16x8 af[4], bfq[4];
#pragma unroll
    for (int i = 0; i < 4; ++i) {
      int row = row0 + wr*64 + i*16 + l15;
      af[i] = *reinterpret_cast<const f16x8*>(&xe16[(long)row*KP + ks*32 + lk*8]);
    }
#pragma unroll
    for (int j = 0; j < 4; ++j) {
      int g = col0 + wc*64 + j*16 + l15;
      bfq[j] = *reinterpret_cast<const f16x8*>(&W16[(long)g*KP + ks*32 + lk*8]);
    }
#pragma unroll
    for (int i = 0; i < 4; ++i)
#pragma unroll
      for (int j = 0; j < 4; ++j)
        acc[i][j] = __builtin_amdgcn_mfma_f32_16x16x32_f16(af[i], bfq[j], acc[i][j], 0, 0, 0);
  }

#pragma unroll
  for (int j = 0; j < 4; ++j) {
    int gcol = col0 + wc*64 + j*16 + l15;
    float bj = (gcol < G3) ? bf[gcol] : bb[gcol - G3];
#pragma unroll
    for (int i = 0; i < 4; ++i) {
      int grow0 = row0 + wr*64 + i*16 + lk*4;
#pragma unroll
      for (int q = 0; q < 4; ++q)
        gi[(long)(grow0 + q)*GIC + gcol] = acc[i][j][q] + bj;
    }
  }
}

// ======== GRU scan v9: u-pair x 4-way-k intra-wave split. 512 thr = 8 waves;
// lane = ul(0..15) | ks(0..3)<<4; thread owns u0=w*32+ul*2, u1=u0+1, k-quarter ks.
// 8 ds_read_b128/thread/step (half of v6); h blocks padded to 72 halves so the 4
// per-wave broadcast addresses hit distinct banks. 192 weight h2 regs (proven).
#define D6(g,e) h2_t W##g##e##00,W##g##e##01,W##g##e##02,W##g##e##10,W##g##e##11,W##g##e##12;
#define DECL24(g) D6(g,a) D6(g,b) D6(g,c) D6(g,d)
#define L6(g,e,p) \
  W##g##e##00=wp[((p)*6+0)*512]; W##g##e##01=wp[((p)*6+1)*512]; W##g##e##02=wp[((p)*6+2)*512]; \
  W##g##e##10=wp[((p)*6+3)*512]; W##g##e##11=wp[((p)*6+4)*512]; W##g##e##12=wp[((p)*6+5)*512];
#define LOAD24(g) L6(g,a,4*(g)+0) L6(g,b,4*(g)+1) L6(g,c,4*(g)+2) L6(g,d,4*(g)+3)
#define F6(g,e,HE) \
  b0a0=FDOT(W##g##e##00,(HE),b0a0); b0a1=FDOT(W##g##e##01,(HE),b0a1); b0a2=FDOT(W##g##e##02,(HE),b0a2); \
  b1a0=FDOT(W##g##e##10,(HE),b1a0); b1a1=FDOT(W##g##e##11,(HE),b1a1); b1a2=FDOT(W##g##e##12,(HE),b1a2);
#define FMA24(g) { H8 hv = *reinterpret_cast<const H8*>(&hr[(g)*8]); \
  F6(g,a,hv.a) F6(g,b,hv.b) F6(g,c,hv.c) F6(g,d,hv.d) }
#define GRP8X(M) M(0) M(1) M(2) M(3) M(4) M(5) M(6) M(7)

__global__ __launch_bounds__(512)
__attribute__((amdgpu_waves_per_eu(2, 2)))
void k_scan_reg9(const float* __restrict__ gi,
     const h2_t* __restrict__ Wpk,
     const float* __restrict__ bhf, const float* __restrict__ bhb,
     float* __restrict__ hseq){
  __shared__ __align__(16) half1 hist[129*288];  // 4 blocks x 72 halves per row; 74KB
  const int t    = threadIdx.x;
  const int lane = t & 63;
  const int ul   = lane & 15;
  const int ks   = lane >> 4;          // 0..3
  const int w    = t >> 6;
  const int u0   = w*32 + ul*2;
  const int dir  = blockIdx.x & 1;
  const int b    = blockIdx.x >> 1;
  const float* bhh = dir ? bhb : bhf;
  const h2_t* wp = Wpk + (long)dir*98304 + t;

  GRP8X(DECL24)
  GRP8X(LOAD24)

  const bool fin = (ks == 0);
  float bh00=0.f, bh01=0.f, bh10=0.f, bh11=0.f, bh20=0.f, bh21=0.f;
  if (fin) {
    float2 v0 = *reinterpret_cast<const float2*>(&bhh[u0]);
    float2 v1 = *reinterpret_cast<const float2*>(&bhh[HID+u0]);
    float2 v2 = *reinterpret_cast<const float2*>(&bhh[2*HID+u0]);
    bh00 = v0.x; bh01 = v0.y; bh10 = v1.x; bh11 = v1.y; bh20 = v2.x; bh21 = v2.y;
  }
  if (t < 288) hist[t] = (half1)0.f;   // row 0 = h0 = 0 (incl. pads)
  float hprev0 = 0.f, hprev1 = 0.f;

  const long gstep = dir ? -(long)NB*GIC : (long)NB*GIC;
  long gbase = ((long)(dir ? (NS-1) : 0)*NB + b)*GIC + dir*G3 + u0;
  __syncthreads();

#pragma unroll 1
  for (int tt = 0; tt < NS; ++tt) {
    float i00=0.f,i01=0.f,i10=0.f,i11=0.f,i20=0.f,i21=0.f;
    if (fin) {                         // issued before dot phase; used after reduce
      float2 v0 = *reinterpret_cast<const float2*>(&gi[gbase]);
      float2 v1 = *reinterpret_cast<const float2*>(&gi[gbase+HID]);
      float2 v2 = *reinterpret_cast<const float2*>(&gi[gbase+2*HID]);
      i00 = v0.x; i01 = v0.y; i10 = v1.x; i11 = v1.y; i20 = v2.x; i21 = v2.y;
    }
    const half1* hr = &hist[tt*288 + ks*72];
    float b0a0=0.f,b0a1=0.f,b0a2=0.f, b1a0=0.f,b1a1=0.f,b1a2=0.f;
    GRP8X(FMA24)                       // 8 H8 loads, 192 fdot2
    b0a0 += __shfl_xor(b0a0, 16, 64); b0a0 += __shfl_xor(b0a0, 32, 64);
    b0a1 += __shfl_xor(b0a1, 16, 64); b0a1 += __shfl_xor(b0a1, 32, 64);
    b0a2 += __shfl_xor(b0a2, 16, 64); b0a2 += __shfl_xor(b0a2, 32, 64);
    b1a0 += __shfl_xor(b1a0, 16, 64); b1a0 += __shfl_xor(b1a0, 32, 64);
    b1a1 += __shfl_xor(b1a1, 16, 64); b1a1 += __shfl_xor(b1a1, 32, 64);
    b1a2 += __shfl_xor(b1a2, 16, 64); b1a2 += __shfl_xor(b1a2, 32, 64);
    if (fin) {
      float r0  = sigm(i00 + bh00 + b0a0);
      float z0  = sigm(i10 + bh10 + b0a1);
      float n0  = tanh_fast(i20 + bh20 + r0*b0a2);
      float hn0 = (1.f - z0)*n0 + z0*hprev0;
      float r1  = sigm(i01 + bh01 + b1a0);
      float z1  = sigm(i11 + bh11 + b1a1);
      float n1  = tanh_fast(i21 + bh21 + r1*b1a2);
      float hn1 = (1.f - z1)*n1 + z1*hprev1;
      hprev0 = hn0; hprev1 = hn1;
      h2_t hw; hw.x = (half1)hn0; hw.y = (half1)hn1;
      *reinterpret_cast<h2_t*>(&hist[(tt+1)*288 + (u0 >> 6)*72 + (u0 & 63)]) = hw;
    }
    gbase += gstep;
    __syncthreads();                   // row tt+1 visible to all
  }

  // bulk dump: hist rows 1..128 -> hseq (coalesced float4)
#pragma unroll 1
  for (int it = 0; it < 16; ++it) {
    int idx = it*512 + t;              // 0..8191
    int ttr = idx >> 6;                // 0..127
    int c4  = (idx & 63) * 4;          // 0,4,..,252
    int s   = dir ? (NS-1-ttr) : ttr;
    int base = (ttr+1)*288 + (c4 >> 6)*72 + (c4 & 63);
    h2_t p0 = *reinterpret_cast<const h2_t*>(&hist[base]);
    h2_t p1 = *reinterpret_cast<const h2_t*>(&hist[base + 2]);
    float4 v; v.x = (float)p0.x; v.y = (float)p0.y; v.z = (float)p1.x; v.w = (float)p1.y;
    *reinterpret_cast<float4*>(&hseq[((long)b*NS + s)*H2 + dir*HID + c4]) = v;
  }
}

// ---- attention scores via MFMA (unchanged).
__global__ __launch_bounds__(256)
__attribute__((amdgpu_waves_per_eu(4, 4)))
void k_att1_mfma(const float* __restrict__ hseq, const half1* __restrict__ afW16,
    const float* __restrict__ afb, const float* __restrict__ attw,
    const int* __restrict__ z, float* __restrict__ ub){
  __shared__ half1 Ah[32*520];
  __shared__ float red[4*32];
  const int t  = threadIdx.x;
  const int b  = blockIdx.x;
  const int s0 = blockIdx.y * 32;
  const int lane = t & 63, w = t >> 6;
  const int l15 = lane & 15, lk = lane >> 4;

#pragma unroll
  for (int l = 0; l < 64; ++l) {
    int idx = l*256 + t;
    int sl = idx >> 9, c = idx & 511;
    Ah[sl*520 + c] = (half1)hseq[((long)b*NS + s0 + sl)*H2 + c];
  }
  __syncthreads();

  f32x4 acc[2][8];
#pragma unroll
  for (int i = 0; i < 2; ++i)
#pragma unroll
    for (int j = 0; j < 8; ++j) acc[i][j] = (f32x4){0.f,0.f,0.f,0.f};

#pragma unroll 2
  for (int ksn = 0; ksn < 16; ++ksn) {
    f16x8 af[2];
#pragma unroll
    for (int mt = 0; mt < 2; ++mt)
      af[mt] = *reinterpret_cast<const f16x8*>(&Ah[(mt*16 + l15)*520 + ksn*32 + lk*8]);
#pragma unroll
    for (int nt = 0; nt < 8; ++nt) {
      int n = w*128 + nt*16 + l15;
      f16x8 bf = *reinterpret_cast<const f16x8*>(&afW16[(long)n*512 + ksn*32 + lk*8]);
#pragma unroll
      for (int mt = 0; mt < 2; ++mt)
        acc[mt][nt] = __builtin_amdgcn_mfma_f32_16x16x32_f16(af[mt], bf, acc[mt][nt], 0, 0, 0);
    }
  }

  float us[8];
#pragma unroll
  for (int i = 0; i < 8; ++i) us[i] = 0.f;
  const int zb = z[b];
#pragma unroll
  for (int nt = 0; nt < 8; ++nt) {
    int n = w*128 + nt*16 + l15;
    float ab = (n < ATT) ? afb[n] : 0.f;
    float aw = (n < ATT) ? attw[zb*ATT + n] : 0.f;
#pragma unroll
    for (int mt = 0; mt < 2; ++mt)
#pragma unroll
      for (int q = 0; q < 4; ++q)
        us[mt*4+q] += tanh_fast(acc[mt][nt][q] + ab) * aw;
  }
#pragma unroll
  for (int off = 1; off < 16; off <<= 1)
#pragma unroll
    for (int i = 0; i < 8; ++i) us[i] += __shfl_xor(us[i], off, 64);
  if (l15 == 0) {
#pragma unroll
    for (int i = 0; i < 8; ++i) {
      int row = (i >> 2)*16 + lk*4 + (i & 3);
      red[w*32 + row] = us[i];
    }
  }
  __syncthreads();
  if (t < 32)
    ub[b*NS + s0 + t] = red[t] + red[32+t] + red[64+t] + red[96+t];
}

// ---- softmax + pooled + fc (unchanged)
__global__ __launch_bounds__(256) void k_att2(const float* __restrict__ hseq,
   const float* __restrict__ ub, const float* __restrict__ fcW,
   const float* __restrict__ fcb, float* __restrict__ out){
  __shared__ float att[NS];
  __shared__ float red[256];
  __shared__ float pool[H2];
  const int t = threadIdx.x, b = blockIdx.x;
  float v = (t < NS) ? ub[b*NS + t] : -3.4e38f;
  red[t] = v; __syncthreads();
  for (int off = 128; off >= 1; off >>= 1) {
    if (t < off) red[t] = fmaxf(red[t], red[t+off]);
    __syncthreads();
  }
  float mx = red[0]; __syncthreads();
  float e = (t < NS) ? EXP2F(1.44269504f*(v - mx)) : 0.f;
  red[t] = e; __syncthreads();
  for (int off = 128; off >= 1; off >>= 1) {
    if (t < off) red[t] += red[t+off];
    __syncthreads();
  }
  float sm = red[0]; __syncthreads();
  if (t < NS) att[t] = e / sm;
  __syncthreads();
#pragma unroll
  for (int rep = 0; rep < 2; ++rep) {
    int c = rep*256 + t;
    float acc = 0.f;
#pragma unroll 4
    for (int s = 0; s < NS; ++s) acc += att[s] * hseq[((long)b*NS + s)*H2 + c];
    pool[c] = acc;
  }
  __syncthreads();
  for (int j = 0; j < 2; ++j) {
    float p = pool[t]*fcW[j*H2+t] + pool[t+256]*fcW[j*H2+t+256];
    red[t] = p; __syncthreads();
    for (int off = 128; off >= 1; off >>= 1) {
      if (t < off) red[t] += red[t+off];
      __syncthreads();
    }
    if (t == 0) out[b*2+j] = red[0] + fcb[j];
    __syncthreads();
  }
}

extern "C" void kernel_launch(void* const* d_in, const int* in_sizes, int n_in,
                              void* d_out, int out_size, void* d_ws, size_t ws_size,
                              hipStream_t stream) {
  const int*   x     = (const int*)  d_in[0];
  const int*   z     = (const int*)  d_in[1];
  const float* emb   = (const float*)d_in[2];
  const float* Wih_f = (const float*)d_in[3];
  const float* Whh_f = (const float*)d_in[4];
  const float* bih_f = (const float*)d_in[5];
  const float* bhh_f = (const float*)d_in[6];
  const float* Wih_b = (const float*)d_in[7];
  const float* Whh_b = (const float*)d_in[8];
  const float* bih_b = (const float*)d_in[9];
  const float* bhh_b = (const float*)d_in[10];
  const float* afW   = (const float*)d_in[11];
  const float* afb   = (const float*)d_in[12];
  const float* attw  = (const float*)d_in[13];
  const float* fcW   = (const float*)d_in[14];
  const float* fcb   = (const float*)d_in[15];

  float* ws    = (float*)d_ws;
  h2_t*  Wpk   = (h2_t*)ws;                        // 196608 slots (4B each)
  half1* afW16 = (half1*)(ws + 196608);            // 512*512 halves = 131072 f
  float* giW   = ws   + 196608 + 131072;           // 8192*1536 = 12582912 f
  float* hseq  = giW  + 12582912;                  // 64*128*512 = 4194304 f
  float* ubuf  = hseq + 4194304;                   // 64*128
  // xe16/W16 alias the hseq region: consumed by k_gi16f BEFORE scan writes hseq.
  h2_t*  xe16  = (h2_t*)hseq;                      // 8192*160 h2 = 1310720 f
  h2_t*  W16   = (h2_t*)(hseq + 1310720);          // 1536*160 h2 = 245760 f

  // merged prep: Wpk + afW16 + xe16 + W16 in one launch
  const int prep_total = N_WPK + N_AFW + N_XE + N_W16;   // 2,015,232
  k_prep_all<<<dim3((prep_total + 255)/256), dim3(256), 0, stream>>>(
      x, emb, Wih_f, Wih_b, Whh_f, Whh_b, afW, Wpk, afW16, xe16, W16);
  k_gi16f <<<dim3(64,12), dim3(256), 0, stream>>>((const half1*)xe16, (const half1*)W16,
                                                  bih_f, bih_b, giW);
  k_scan_reg9<<<dim3(128), dim3(512), 0, stream>>>(giW, Wpk, bhh_f, bhh_b, hseq);
  k_att1_mfma<<<dim3(64,4), dim3(256), 0, stream>>>(hseq, afW16, afb, attw, z, ubuf);
  k_att2<<<dim3(64), dim3(256), 0, stream>>>(hseq, ubuf, fcW, fcb, (float*)d_out);
}